// Round 1
// baseline (106.640 us; speedup 1.0000x reference)
//
#include <hip/hip_runtime.h>

typedef __bf16 bf16x8 __attribute__((ext_vector_type(8)));
typedef __bf16 bf16x4 __attribute__((ext_vector_type(4)));
typedef float  f32x4  __attribute__((ext_vector_type(4)));

#define MFMA16(a, b, c) __builtin_amdgcn_mfma_f32_16x16x32_bf16((a), (b), (c), 0, 0, 0)

// ---------------------------------------------------------------------------
// Problem constants
// ---------------------------------------------------------------------------
#define B_   4
#define NS_  128
#define GS_  8
#define DM_  512
#define MH_  8      // heads
#define DK_  64     // head dim
#define L_   1024   // NS*GS tokens per batch
#define NT_  4096   // B * L total tokens

// ---------------------------------------------------------------------------
// LayerNorm: X f32 [4096,512] -> Xn bf16 [4096,512]
// one block per token, 256 threads (2 elems/thread)
// ---------------------------------------------------------------------------
__global__ __launch_bounds__(256) void ln_kernel(const float* __restrict__ X,
                                                 const float* __restrict__ g,
                                                 const float* __restrict__ be,
                                                 __bf16* __restrict__ Xn) {
  const int t   = blockIdx.x;
  const int tid = threadIdx.x;
  const long base = (long)t * DM_;
  const float x0 = X[base + tid];
  const float x1 = X[base + 256 + tid];
  float s  = x0 + x1;
  float sq = x0 * x0 + x1 * x1;
#pragma unroll
  for (int off = 1; off < 64; off <<= 1) {
    s  += __shfl_xor(s, off);
    sq += __shfl_xor(sq, off);
  }
  __shared__ float red[8];
  if ((tid & 63) == 0) {
    red[(tid >> 6) * 2]     = s;
    red[(tid >> 6) * 2 + 1] = sq;
  }
  __syncthreads();
  s  = red[0] + red[2] + red[4] + red[6];
  sq = red[1] + red[3] + red[5] + red[7];
  const float mu   = s * (1.0f / DM_);
  const float var  = sq * (1.0f / DM_) - mu * mu;
  const float rstd = rsqrtf(var + 1e-5f);
  Xn[base + tid]       = (__bf16)((x0 - mu) * rstd * g[tid] + be[tid]);
  Xn[base + 256 + tid] = (__bf16)((x1 - mu) * rstd * g[tid + 256] + be[tid + 256]);
}

// ---------------------------------------------------------------------------
// f32 -> bf16 cast (weights), n divisible by 4
// ---------------------------------------------------------------------------
__global__ __launch_bounds__(256) void cast_bf16(const float* __restrict__ src,
                                                 __bf16* __restrict__ dst, int n) {
  const int i = (blockIdx.x * 256 + threadIdx.x) * 4;
  if (i < n) {
    const float4 v = *(const float4*)(src + i);
    bf16x4 o;
    o[0] = (__bf16)v.x; o[1] = (__bf16)v.y; o[2] = (__bf16)v.z; o[3] = (__bf16)v.w;
    *(bf16x4*)(dst + i) = o;
  }
}

// ---------------------------------------------------------------------------
// GEMM C[M,N] = A[M,K] * Bw[N,K]^T  (both row-major bf16, K inner)
// block 256 (4 waves, 2x2), tile 64x64, BK=32
// mode 0: Cb[row*N+col] = bf16( (acc+bias[col]) * scale )
// mode 1: Cf[row*N+col] = (acc+bias[col])*scale + residual[row*N+col]   (f32)
// ---------------------------------------------------------------------------
__global__ __launch_bounds__(256) void gemm_bt(const __bf16* __restrict__ A,
                                               const __bf16* __restrict__ Bw,
                                               const float* __restrict__ bias,
                                               const float* __restrict__ residual,
                                               float* __restrict__ Cf,
                                               __bf16* __restrict__ Cb,
                                               int M_, int N_, int K_,
                                               float scale, int mode) {
  __shared__ __bf16 As[64][40];   // +8 pad: row stride 80B, 16B-aligned
  __shared__ __bf16 Bs[64][40];
  const int tid = threadIdx.x;
  const int l   = tid & 63;
  const int w   = tid >> 6;
  const int wm  = w >> 1, wn = w & 1;
  const int bm  = blockIdx.x, bn = blockIdx.y;
  const int lrow = tid >> 2;         // 0..63
  const int lcol = (tid & 3) * 8;    // 0,8,16,24
  const long arow = (long)(bm * 64 + lrow) * K_;
  const long brow = (long)(bn * 64 + lrow) * K_;
  const int r16 = l & 15;
  const int kk8 = (l >> 4) * 8;

  f32x4 acc[2][2] = {};
  for (int k0 = 0; k0 < K_; k0 += 32) {
    const bf16x8 va = *(const bf16x8*)(A + arow + k0 + lcol);
    const bf16x8 vb = *(const bf16x8*)(Bw + brow + k0 + lcol);
    __syncthreads();
    *(bf16x8*)(&As[lrow][lcol]) = va;
    *(bf16x8*)(&Bs[lrow][lcol]) = vb;
    __syncthreads();
    bf16x8 af0 = *(const bf16x8*)(&As[wm * 32 + r16][kk8]);
    bf16x8 af1 = *(const bf16x8*)(&As[wm * 32 + 16 + r16][kk8]);
    bf16x8 bf0 = *(const bf16x8*)(&Bs[wn * 32 + r16][kk8]);
    bf16x8 bf1 = *(const bf16x8*)(&Bs[wn * 32 + 16 + r16][kk8]);
    acc[0][0] = MFMA16(af0, bf0, acc[0][0]);
    acc[0][1] = MFMA16(af0, bf1, acc[0][1]);
    acc[1][0] = MFMA16(af1, bf0, acc[1][0]);
    acc[1][1] = MFMA16(af1, bf1, acc[1][1]);
  }
  const int rq = (l >> 4) * 4;
#pragma unroll
  for (int am = 0; am < 2; ++am)
#pragma unroll
    for (int bi = 0; bi < 2; ++bi)
#pragma unroll
      for (int r = 0; r < 4; ++r) {
        const int row = bm * 64 + wm * 32 + am * 16 + rq + r;
        const int col = bn * 64 + wn * 32 + bi * 16 + r16;
        const float v = (acc[am][bi][r] + bias[col]) * scale;
        if (mode == 0) Cb[(long)row * N_ + col] = (__bf16)v;
        else           Cf[(long)row * N_ + col] = v + residual[(long)row * N_ + col];
      }
}

// ---------------------------------------------------------------------------
// Flash attention per (q-tile=64, head m, batch b) with relative bias.
// 256 threads = 4 waves; wave w owns q rows [qt*64+w*16, +16).
// Q pre-scaled by 1/sqrt(dk). KV tiles of 64.
// bias(q=(i,g), t=(j,k)) = rho[ sd[i,j]*8 + gm[g,k] ][m]
// ---------------------------------------------------------------------------
__global__ __launch_bounds__(256) void attn_kernel(const __bf16* __restrict__ Q,
                                                   const __bf16* __restrict__ Kb,
                                                   const __bf16* __restrict__ Vb,
                                                   const int* __restrict__ sd,
                                                   const int* __restrict__ gmul,
                                                   const float* __restrict__ rho,
                                                   __bf16* __restrict__ O) {
  __shared__ __bf16 Ks[64][72];       // K tile  [t][d], +8 pad
  __shared__ __bf16 Vt[64][72];       // V^T tile [d][t], +8 pad
  __shared__ __bf16 Ps[4][16][72];    // per-wave P tile [q][t]
  __shared__ float  rho_m[1024];
  __shared__ int    sd_loc[8 * 128];
  __shared__ int    gm_loc[64];

  const int tid = threadIdx.x;
  const int l   = tid & 63;
  const int w   = tid >> 6;
  const int qt  = blockIdx.x;   // 0..15
  const int m   = blockIdx.y;   // 0..7
  const int b   = blockIdx.z;   // 0..3

  for (int p = tid; p < 1024; p += 256) rho_m[p] = rho[p * MH_ + m];
  for (int p = tid; p < 1024; p += 256) {
    const int i_loc = p >> 7, j = p & 127;
    sd_loc[p] = sd[(qt * 8 + i_loc) * NS_ + j];
  }
  if (tid < 64) gm_loc[tid] = gmul[tid];

  const int r16 = l & 15;
  const int kk8 = (l >> 4) * 8;

  // Q fragments (A-operand): row = l&15, k = (l>>4)*8 + j
  const long qrow = ((long)(b * L_ + qt * 64 + w * 16 + r16)) * DM_ + m * DK_;
  bf16x8 aq0 = *(const bf16x8*)(Q + qrow + kk8);
  bf16x8 aq1 = *(const bf16x8*)(Q + qrow + 32 + kk8);

  f32x4 acc_o[4] = {};
  float m_run[4], l_run[4];
#pragma unroll
  for (int r = 0; r < 4; ++r) { m_run[r] = -1e30f; l_run[r] = 0.0f; }

  const int srow = tid >> 2;        // 0..63
  const int scol = (tid & 3) * 8;   // 0,8,16,24

  for (int kv = 0; kv < 16; ++kv) {
    const long kbase = ((long)(b * L_ + kv * 64 + srow)) * DM_ + m * DK_;
    const bf16x8 k0 = *(const bf16x8*)(Kb + kbase + scol);
    const bf16x8 k1 = *(const bf16x8*)(Kb + kbase + 32 + scol);
    const bf16x8 v0 = *(const bf16x8*)(Vb + kbase + scol);
    const bf16x8 v1 = *(const bf16x8*)(Vb + kbase + 32 + scol);
    __syncthreads();   // previous tile fully consumed (also covers init tables at kv=0)
    *(bf16x8*)(&Ks[srow][scol])      = k0;
    *(bf16x8*)(&Ks[srow][scol + 32]) = k1;
#pragma unroll
    for (int e = 0; e < 8; ++e) {
      Vt[scol + e][srow]      = v0[e];
      Vt[scol + 32 + e][srow] = v1[e];
    }
    __syncthreads();

    // S = Q K^T  (16 q rows x 64 t cols per wave)
    f32x4 s4[4];
#pragma unroll
    for (int nf = 0; nf < 4; ++nf) {
      f32x4 acc = {};
      bf16x8 bk0 = *(const bf16x8*)(&Ks[nf * 16 + r16][kk8]);
      bf16x8 bk1 = *(const bf16x8*)(&Ks[nf * 16 + r16][32 + kk8]);
      acc = MFMA16(aq0, bk0, acc);
      acc = MFMA16(aq1, bk1, acc);
      s4[nf] = acc;
    }

    // bias + running max
    float mloc[4];
#pragma unroll
    for (int r = 0; r < 4; ++r) mloc[r] = -1e30f;
#pragma unroll
    for (int nf = 0; nf < 4; ++nf) {
      const int t_glob = kv * 64 + nf * 16 + r16;
      const int j = t_glob >> 3, k = t_glob & 7;
#pragma unroll
      for (int r = 0; r < 4; ++r) {
        const int rq = 4 * (l >> 4) + r;        // q row within wave's 16
        const int i_loc = (w * 16 + rq) >> 3;   // 0..7
        const int g = rq & 7;
        const float bia = rho_m[sd_loc[i_loc * 128 + j] * 8 + gm_loc[g * 8 + k]];
        const float v = s4[nf][r] + bia;
        s4[nf][r] = v;
        mloc[r] = fmaxf(mloc[r], v);
      }
    }
#pragma unroll
    for (int r = 0; r < 4; ++r)
#pragma unroll
      for (int off = 1; off < 16; off <<= 1)
        mloc[r] = fmaxf(mloc[r], __shfl_xor(mloc[r], off));

    float alpha[4];
#pragma unroll
    for (int r = 0; r < 4; ++r) {
      const float mn = fmaxf(m_run[r], mloc[r]);
      alpha[r] = __expf(m_run[r] - mn);
      m_run[r] = mn;
    }
    float ps[4] = {0.f, 0.f, 0.f, 0.f};
#pragma unroll
    for (int nf = 0; nf < 4; ++nf)
#pragma unroll
      for (int r = 0; r < 4; ++r) {
        const float p = __expf(s4[nf][r] - m_run[r]);
        s4[nf][r] = p;
        ps[r] += p;
      }
#pragma unroll
    for (int r = 0; r < 4; ++r)
#pragma unroll
      for (int off = 1; off < 16; off <<= 1)
        ps[r] += __shfl_xor(ps[r], off);
#pragma unroll
    for (int r = 0; r < 4; ++r) l_run[r] = l_run[r] * alpha[r] + ps[r];

    // rescale O, write P tile (C layout -> LDS row-major [q][t])
#pragma unroll
    for (int nf = 0; nf < 4; ++nf)
#pragma unroll
      for (int r = 0; r < 4; ++r) acc_o[nf][r] *= alpha[r];
#pragma unroll
    for (int nf = 0; nf < 4; ++nf)
#pragma unroll
      for (int r = 0; r < 4; ++r)
        Ps[w][4 * (l >> 4) + r][nf * 16 + r16] = (__bf16)s4[nf][r];

    // PV: O[16q x 64d] += P[16q x 64t] * V[64t x 64d]
    bf16x8 ap0 = *(const bf16x8*)(&Ps[w][r16][kk8]);
    bf16x8 ap1 = *(const bf16x8*)(&Ps[w][r16][32 + kk8]);
#pragma unroll
    for (int nf = 0; nf < 4; ++nf) {
      bf16x8 bv0 = *(const bf16x8*)(&Vt[nf * 16 + r16][kk8]);
      bf16x8 bv1 = *(const bf16x8*)(&Vt[nf * 16 + r16][32 + kk8]);
      acc_o[nf] = MFMA16(ap0, bv0, acc_o[nf]);
      acc_o[nf] = MFMA16(ap1, bv1, acc_o[nf]);
    }
  }

  // normalize + write O (bf16, feeds final GEMM)
#pragma unroll
  for (int r = 0; r < 4; ++r) {
    const float inv = 1.0f / l_run[r];
    const int row = qt * 64 + w * 16 + 4 * (l >> 4) + r;
    const long obase = ((long)(b * L_ + row)) * DM_ + m * DK_;
#pragma unroll
    for (int nf = 0; nf < 4; ++nf)
      O[obase + nf * 16 + r16] = (__bf16)(acc_o[nf][r] * inv);
  }
}

// ---------------------------------------------------------------------------
// launch
// ---------------------------------------------------------------------------
extern "C" void kernel_launch(void* const* d_in, const int* in_sizes, int n_in,
                              void* d_out, int out_size, void* d_ws, size_t ws_size,
                              hipStream_t stream) {
  const float* X    = (const float*)d_in[0];
  const int*   sd   = (const int*)d_in[1];
  const int*   gmul = (const int*)d_in[2];
  const float* Wq   = (const float*)d_in[3];
  const float* bq   = (const float*)d_in[4];
  const float* Wk   = (const float*)d_in[5];
  const float* bk   = (const float*)d_in[6];
  const float* Wv   = (const float*)d_in[7];
  const float* bv   = (const float*)d_in[8];
  const float* Wo   = (const float*)d_in[9];
  const float* bo   = (const float*)d_in[10];
  const float* rho  = (const float*)d_in[11];
  const float* ln_g = (const float*)d_in[12];
  const float* ln_b = (const float*)d_in[13];
  float* out = (float*)d_out;

  char* ws = (char*)d_ws;
  const size_t SZ_TOK = (size_t)NT_ * DM_ * 2;  // 4 MB bf16
  __bf16* Xn  = (__bf16*)(ws);
  __bf16* Qb  = (__bf16*)(ws + SZ_TOK);
  __bf16* Kb  = (__bf16*)(ws + 2 * SZ_TOK);
  __bf16* Vb  = (__bf16*)(ws + 3 * SZ_TOK);
  __bf16* Ob  = (__bf16*)(ws + 4 * SZ_TOK);
  __bf16* Wqb = (__bf16*)(ws + 5 * SZ_TOK);
  __bf16* Wkb = (__bf16*)(ws + 5 * SZ_TOK + 512 * 1024);
  __bf16* Wvb = (__bf16*)(ws + 5 * SZ_TOK + 1024 * 1024);
  __bf16* Wob = (__bf16*)(ws + 5 * SZ_TOK + 1536 * 1024);

  const int NW = DM_ * DM_;  // 262144 weight elems

  ln_kernel<<<NT_, 256, 0, stream>>>(X, ln_g, ln_b, Xn);
  cast_bf16<<<NW / 1024, 256, 0, stream>>>(Wq, Wqb, NW);
  cast_bf16<<<NW / 1024, 256, 0, stream>>>(Wk, Wkb, NW);
  cast_bf16<<<NW / 1024, 256, 0, stream>>>(Wv, Wvb, NW);
  cast_bf16<<<NW / 1024, 256, 0, stream>>>(Wo, Wob, NW);

  dim3 ggrid(NT_ / 64, DM_ / 64);
  gemm_bt<<<ggrid, 256, 0, stream>>>(Xn, Wqb, bq, nullptr, nullptr, Qb,
                                     NT_, DM_, DM_, 0.125f, 0);
  gemm_bt<<<ggrid, 256, 0, stream>>>(Xn, Wkb, bk, nullptr, nullptr, Kb,
                                     NT_, DM_, DM_, 1.0f, 0);
  gemm_bt<<<ggrid, 256, 0, stream>>>(Xn, Wvb, bv, nullptr, nullptr, Vb,
                                     NT_, DM_, DM_, 1.0f, 0);

  attn_kernel<<<dim3(L_ / 64, MH_, B_), 256, 0, stream>>>(Qb, Kb, Vb, sd, gmul, rho, Ob);

  gemm_bt<<<ggrid, 256, 0, stream>>>(Ob, Wob, bo, X, out, nullptr,
                                     NT_, DM_, DM_, 1.0f, 1);
}